// Round 1
// baseline (693.573 us; speedup 1.0000x reference)
//
#include <hip/hip_runtime.h>
#include <stdint.h>

using f4v = __attribute__((ext_vector_type(4))) float;
using s8v = __attribute__((ext_vector_type(8))) short;

constexpr int N_ = 16, C_ = 128, H_ = 128, W_ = 128, HW_ = H_ * W_;
constexpr int TS = 16, HALO = 5, INS = TS + 2 * HALO;  // 26
constexpr int GCH = 8, NG = C_ / GCH;                  // 8 ch/block, 16 groups

__device__ __forceinline__ unsigned short f2bf(float f) {
  union { float f; unsigned u; } v; v.f = f;
  unsigned r = v.u + 0x7FFFu + ((v.u >> 16) & 1u);   // RTNE
  return (unsigned short)(r >> 16);
}

// ---------------- Kernel 1: fused depthwise branches -> add (bf16, blocked layout) ----
// ws layout: [n][g=c/8][p=h*128+w][c%8] bf16  (16B per pixel-group: K2 B-frag friendly)
__global__ __launch_bounds__(256) void k_dw(
    const float* __restrict__ x,
    const float* __restrict__ w0,  const float* __restrict__ b0,
    const float* __restrict__ w01, const float* __restrict__ b01,
    const float* __restrict__ w02, const float* __restrict__ b02,
    const float* __restrict__ w11, const float* __restrict__ b11,
    const float* __restrict__ w12, const float* __restrict__ b12,
    unsigned short* __restrict__ ws)
{
  __shared__ float in_s[GCH][INS][28];   // halo-5 tile, padded cols
  __shared__ float h5s[GCH][20][16];     // horiz 1x5 result, rows rel in-row 3..22
  __shared__ float h11s[GCH][26][16];    // horiz 1x11 result, rows rel in-row 0..25
  __shared__ float wgt[GCH][41];         // 0..8:w0 9..13:w01 14..18:w02 19..29:w11 30..40:w12
  __shared__ float bss[GCH][3];          // [0]=b0+b02+b12, [1]=b01, [2]=b11

  const int t = threadIdx.x;
  const int tile = blockIdx.x, g = blockIdx.y, n = blockIdx.z;
  const int ty = tile >> 3, tx = tile & 7;
  const int h0 = ty * TS, w0p = tx * TS;
  const int c0 = g * GCH;

  for (int i = t; i < GCH * 41; i += 256) {
    int ch = i / 41, widx = i - ch * 41;
    int c = c0 + ch;
    float v;
    if      (widx < 9)  v = w0 [c * 9  + widx];
    else if (widx < 14) v = w01[c * 5  + widx - 9];
    else if (widx < 19) v = w02[c * 5  + widx - 14];
    else if (widx < 30) v = w11[c * 11 + widx - 19];
    else                v = w12[c * 11 + widx - 30];
    wgt[ch][widx] = v;
  }
  if (t < GCH) {
    int c = c0 + t;
    bss[t][0] = b0[c] + b02[c] + b12[c];
    bss[t][1] = b01[c];
    bss[t][2] = b11[c];
  }

  for (int i = t; i < GCH * INS * INS; i += 256) {
    int ch = i / (INS * INS);
    int rem = i - ch * (INS * INS);
    int r = rem / INS, cc = rem - r * INS;
    int gy = h0 - HALO + r, gx = w0p - HALO + cc;
    float v = 0.f;
    if ((unsigned)gy < (unsigned)H_ && (unsigned)gx < (unsigned)W_)
      v = x[((n * C_ + c0 + ch) * H_ + gy) * W_ + gx];
    in_s[ch][r][cc] = v;
  }
  __syncthreads();

  // horizontal 1x11 over all 26 rows (in-row r -> global h0-5+r)
  for (int i = t; i < GCH * 26 * 16; i += 256) {
    int ch = i / 416, rem = i - ch * 416;
    int r = rem >> 4, xx = rem & 15;
    float a = 0.f;
#pragma unroll
    for (int k = 0; k < 11; ++k) a += wgt[ch][19 + k] * in_s[ch][r][xx + k];
    h11s[ch][r][xx] = a;
  }
  // horizontal 1x5 over rows rel 3..22 (20 rows)
  for (int i = t; i < GCH * 20 * 16; i += 256) {
    int ch = i / 320, rem = i - ch * 320;
    int r = rem >> 4, xx = rem & 15;
    float a = 0.f;
#pragma unroll
    for (int k = 0; k < 5; ++k) a += wgt[ch][9 + k] * in_s[ch][r + 3][xx + 3 + k];
    h5s[ch][r][xx] = a;
  }
  __syncthreads();

  const int y = t >> 4, xx = t & 15;
  const int gy = h0 + y, gx = w0p + xx;
  unsigned short res[8];
#pragma unroll
  for (int ch = 0; ch < GCH; ++ch) {
    float v5 = 0.f, s5 = 0.f;
#pragma unroll
    for (int k = 0; k < 5; ++k) {
      v5 += wgt[ch][14 + k] * h5s[ch][y + k][xx];
      int rr = gy - 2 + k;
      if (rr >= 0 && rr < H_) s5 += wgt[ch][14 + k];   // b01 passes only through in-bounds taps
    }
    float v11 = 0.f, s11 = 0.f;
#pragma unroll
    for (int k = 0; k < 11; ++k) {
      v11 += wgt[ch][30 + k] * h11s[ch][y + k][xx];
      int rr = gy - 5 + k;
      if (rr >= 0 && rr < H_) s11 += wgt[ch][30 + k];
    }
    float c33 = 0.f;
#pragma unroll
    for (int i = 0; i < 3; ++i)
#pragma unroll
      for (int j = 0; j < 3; ++j)
        c33 += wgt[ch][i * 3 + j] * in_s[ch][y + 4 + i][xx + 4 + j];
    float addv = c33 + v5 + v11 + bss[ch][0] + bss[ch][1] * s5 + bss[ch][2] * s11;
    res[ch] = f2bf(addv);
  }
  const int p = gy * W_ + gx;
  uint4 pk;
  pk.x = (unsigned)res[0] | ((unsigned)res[1] << 16);
  pk.y = (unsigned)res[2] | ((unsigned)res[3] << 16);
  pk.z = (unsigned)res[4] | ((unsigned)res[5] << 16);
  pk.w = (unsigned)res[6] | ((unsigned)res[7] << 16);
  *reinterpret_cast<uint4*>(ws + ((size_t)(n * NG + g) * HW_ + p) * 8) = pk;
}

// ---------------- Kernel 2: 1x1 channel mix via MFMA + multiply by x -----------------
// block = (hrow, n): all 128 outputs x 128 pixels (one image row). 4 waves x 32 pixels.
__global__ __launch_bounds__(256) void k_mix(
    const float* __restrict__ x,
    const float* __restrict__ w3, const float* __restrict__ b3,
    const unsigned short* __restrict__ ws,
    float* __restrict__ out)
{
  __shared__ __align__(16) unsigned short a_lds[128 * 136];  // w3 bf16, padded stride
  __shared__ float b3s[128];
  const int t = threadIdx.x;
  const int hrow = blockIdx.x, n = blockIdx.y;

  for (int i = t; i < 128 * 128; i += 256) {
    int o = i >> 7, c = i & 127;
    a_lds[o * 136 + c] = f2bf(w3[i]);
  }
  if (t < 128) b3s[t] = b3[t];
  __syncthreads();

  const int wv = t >> 6, lane = t & 63;
  const int q = lane >> 4, lp = lane & 15;
  const int pbase = hrow * 128 + wv * 32;

  f4v acc[8][2] = {};
  const unsigned short* wsn = ws + (size_t)n * NG * HW_ * 8;

#pragma unroll
  for (int ks = 0; ks < 4; ++ks) {
    const int gg = ks * 4 + q;          // channel group for this lane-quad
    s8v bfrag[2];
#pragma unroll
    for (int nt = 0; nt < 2; ++nt) {
      int p = pbase + nt * 16 + lp;
      bfrag[nt] = *reinterpret_cast<const s8v*>(wsn + ((size_t)gg * HW_ + p) * 8);
    }
    const int crow = ks * 32 + q * 8;
#pragma unroll
    for (int mt = 0; mt < 8; ++mt) {
      int o = mt * 16 + lp;
      s8v afrag = *reinterpret_cast<const s8v*>(a_lds + o * 136 + crow);
      acc[mt][0] = __builtin_amdgcn_mfma_f32_16x16x32_bf16(afrag, bfrag[0], acc[mt][0], 0, 0, 0);
      acc[mt][1] = __builtin_amdgcn_mfma_f32_16x16x32_bf16(afrag, bfrag[1], acc[mt][1], 0, 0, 0);
    }
  }

#pragma unroll
  for (int mt = 0; mt < 8; ++mt)
#pragma unroll
    for (int nt = 0; nt < 2; ++nt)
#pragma unroll
      for (int r = 0; r < 4; ++r) {
        int o = mt * 16 + q * 4 + r;       // D: row = quad*4+reg (+mt*16)
        int p = pbase + nt * 16 + lp;      // D: col = lane&15
        int idx = (n * C_ + o) * HW_ + p;
        float v = acc[mt][nt][r] + b3s[o];
        out[idx] = v * x[idx];
      }
}

extern "C" void kernel_launch(void* const* d_in, const int* in_sizes, int n_in,
                              void* d_out, int out_size, void* d_ws, size_t ws_size,
                              hipStream_t stream) {
  const float* x   = (const float*)d_in[0];
  const float* w0  = (const float*)d_in[1];
  const float* b0  = (const float*)d_in[2];
  const float* w01 = (const float*)d_in[3];
  const float* b01 = (const float*)d_in[4];
  const float* w02 = (const float*)d_in[5];
  const float* b02 = (const float*)d_in[6];
  const float* w11 = (const float*)d_in[7];
  const float* b11 = (const float*)d_in[8];
  const float* w12 = (const float*)d_in[9];
  const float* b12 = (const float*)d_in[10];
  const float* w3  = (const float*)d_in[11];
  const float* b3  = (const float*)d_in[12];
  unsigned short* ws = (unsigned short*)d_ws;   // needs 16*16*16384*8*2 = 64 MiB
  float* out = (float*)d_out;

  dim3 g1(64, NG, N_);     // (spatial tiles 8x8, channel groups, batch)
  k_dw<<<g1, 256, 0, stream>>>(x, w0, b0, w01, b01, w02, b02, w11, b11, w12, b12, ws);

  dim3 g2(H_, N_);         // (image row, batch)
  k_mix<<<g2, 256, 0, stream>>>(x, w3, b3, ws, out);
}

// Round 3
// 563.836 us; speedup vs baseline: 1.2301x; 1.2301x over previous
//
#include <hip/hip_runtime.h>
#include <stdint.h>

using f4v = __attribute__((ext_vector_type(4))) float;
using s8v = __attribute__((ext_vector_type(8))) short;

constexpr int C_ = 128, H_ = 128, W_ = 128, HW_ = H_ * W_;

__device__ __forceinline__ unsigned f2bf(float f) {
  union { float f; unsigned u; } v; v.f = f;
  return (v.u + 0x7FFFu + ((v.u >> 16) & 1u)) >> 16;   // RTNE
}

// ---------------------------------------------------------------------------
// Kernel 1: fused depthwise branches -> add (bf16), column-sweep with circular
// register accumulators. Block = 8 channels x 32-col strip; thread owns (c,x),
// sweeps y. ws layout: [n][g=c/8][p=h*128+w][c%8] bf16 (16B per pixel-group).
// ---------------------------------------------------------------------------
__global__ __launch_bounds__(256) void k_dw(
    const float* __restrict__ x,
    const float* __restrict__ w0,  const float* __restrict__ b0,
    const float* __restrict__ w01, const float* __restrict__ b01,
    const float* __restrict__ w02, const float* __restrict__ b02,
    const float* __restrict__ w11, const float* __restrict__ b11,
    const float* __restrict__ w12, const float* __restrict__ b12,
    unsigned short* __restrict__ ws)
{
  __shared__ float xs[8][16][48];            // 16-row chunk + 8-col halo each side (zero-padded)
  __shared__ unsigned short ebuf[16][8][32]; // emit transpose buffer [row][ch][x]
  __shared__ float bias_row[8][128];         // b0+b02+b12 + b01*s5(y) + b11*s11(y)

  const int t = threadIdx.x;
  const int xstrip = blockIdx.x, g = blockIdx.y, n = blockIdx.z;
  const int xbase = xstrip * 32;
  const int c0 = g * 8;
  const int ch = t >> 5, xl = t & 31;
  const int c = c0 + ch;

  // per-thread weights in registers (41 floats)
  float w0t[9], w01t[5], w02t[5], w11t[11], w12t[11];
#pragma unroll
  for (int k = 0; k < 9; ++k)  w0t[k] = w0[c * 9 + k];
#pragma unroll
  for (int k = 0; k < 5; ++k)  { w01t[k] = w01[c * 5 + k]; w02t[k] = w02[c * 5 + k]; }
#pragma unroll
  for (int k = 0; k < 11; ++k) { w11t[k] = w11[c * 11 + k]; w12t[k] = w12[c * 11 + k]; }

  // boundary-bias table: depends only on (ch, y)
  for (int id = t; id < 1024; id += 256) {
    int cb = id >> 7, y = id & 127;
    int cc = c0 + cb;
    float s5 = 0.f, s11 = 0.f;
#pragma unroll
    for (int k = 0; k < 5; ++k)  if ((unsigned)(y - 2 + k) < 128u) s5  += w02[cc * 5 + k];
#pragma unroll
    for (int k = 0; k < 11; ++k) if ((unsigned)(y - 5 + k) < 128u) s11 += w12[cc * 11 + k];
    bias_row[cb][y] = b0[cc] + b02[cc] + b12[cc] + b01[cc] * s5 + b11[cc] * s11;
  }

  float acc[16];
#pragma unroll
  for (int i = 0; i < 16; ++i) acc[i] = 0.f;

  unsigned short* wsp = ws + (size_t)(n * 16 + g) * HW_ * 8;

  for (int cidx = 0; cidx < 8; ++cidx) {
    const int y0 = cidx * 16;
    __syncthreads();
    // stage 16 rows x 48 cols x 8 ch (OOB -> 0), float4
#pragma unroll
    for (int i = 0; i < 6; ++i) {
      int id = i * 256 + t;
      int chs = id / 192;
      int rem = id - chs * 192;
      int rs = rem / 12;
      int c4 = rem - rs * 12;
      int gx = xbase - 8 + c4 * 4;
      float4 v = make_float4(0.f, 0.f, 0.f, 0.f);
      if ((unsigned)gx < 128u)
        v = *(const float4*)(x + (size_t)((n * C_ + c0 + chs) * H_ + y0 + rs) * W_ + gx);
      *(float4*)&xs[chs][rs][c4 * 4] = v;
    }
    __syncthreads();
#pragma unroll
    for (int rr = 0; rr < 16; ++rr) {
      float win[11];
#pragma unroll
      for (int k = 0; k < 11; ++k) win[k] = xs[ch][rr][xl + 3 + k];
      // horizontal filters share the window
      float h11 = w11t[0] * win[0];
#pragma unroll
      for (int k = 1; k < 11; ++k) h11 += w11t[k] * win[k];
      float h5 = w01t[0] * win[3];
#pragma unroll
      for (int k = 1; k < 5; ++k) h5 += w01t[k] * win[3 + k];
      float r0 = w0t[0] * win[4] + w0t[1] * win[5] + w0t[2] * win[6];
      float r1 = w0t[3] * win[4] + w0t[4] * win[5] + w0t[5] * win[6];
      float r2 = w0t[6] * win[4] + w0t[7] * win[5] + w0t[8] * win[6];
      // vertical scatter into circular accumulators (compile-time slots)
#pragma unroll
      for (int tt = 0; tt < 11; ++tt) acc[(rr + 5 - tt) & 15] += w12t[tt] * h11;
#pragma unroll
      for (int tt = 0; tt < 5; ++tt)  acc[(rr + 2 - tt) & 15] += w02t[tt] * h5;
      acc[(rr + 1) & 15]  += r0;
      acc[rr & 15]        += r1;
      acc[(rr + 15) & 15] += r2;
      // Top-boundary fix: rows y=0..4 scatter "outputs" o<0 which wrap into
      // slots 11..15 (used later by outputs 11..15). All pollution happens by
      // rr=4; first legit write to those slots is at y=6 (o=11, tap t=10).
      // Zero them exactly once, after rr=4's scatter, in chunk 0 only.
      if (rr == 4 && cidx == 0) {
        acc[11] = 0.f; acc[12] = 0.f; acc[13] = 0.f; acc[14] = 0.f; acc[15] = 0.f;
      }
      // output o = y0+rr-5 is complete
      if (y0 + rr >= 5) {
        const int o = y0 + rr - 5;
        const int slot = (rr + 11) & 15;
        ebuf[rr][ch][xl] = (unsigned short)f2bf(acc[slot] + bias_row[ch][o]);
        acc[slot] = 0.f;
      }
    }
    __syncthreads();
    // cooperative writeout: 16 o-rows, 16B per thread-pixel, contiguous
    for (int id = t; id < 512; id += 256) {
      int orr = id >> 5, x2 = id & 31;
      int o = y0 - 5 + orr;
      if (o >= 0) {
        unsigned u0 = ebuf[orr][0][x2] | ((unsigned)ebuf[orr][1][x2] << 16);
        unsigned u1 = ebuf[orr][2][x2] | ((unsigned)ebuf[orr][3][x2] << 16);
        unsigned u2 = ebuf[orr][4][x2] | ((unsigned)ebuf[orr][5][x2] << 16);
        unsigned u3 = ebuf[orr][6][x2] | ((unsigned)ebuf[orr][7][x2] << 16);
        uint4 pk; pk.x = u0; pk.y = u1; pk.z = u2; pk.w = u3;
        *(uint4*)(wsp + (size_t)(o * W_ + xbase + x2) * 8) = pk;
      }
    }
  }
  // drain outputs 123..127
  __syncthreads();
#pragma unroll
  for (int orr = 0; orr < 5; ++orr) {
    const int o = 123 + orr;
    const int slot = o & 15;
    ebuf[orr][ch][xl] = (unsigned short)f2bf(acc[slot] + bias_row[ch][o]);
  }
  __syncthreads();
  if (t < 160) {
    int orr = t >> 5, x2 = t & 31;
    int o = 123 + orr;
    unsigned u0 = ebuf[orr][0][x2] | ((unsigned)ebuf[orr][1][x2] << 16);
    unsigned u1 = ebuf[orr][2][x2] | ((unsigned)ebuf[orr][3][x2] << 16);
    unsigned u2 = ebuf[orr][4][x2] | ((unsigned)ebuf[orr][5][x2] << 16);
    unsigned u3 = ebuf[orr][6][x2] | ((unsigned)ebuf[orr][7][x2] << 16);
    uint4 pk; pk.x = u0; pk.y = u1; pk.z = u2; pk.w = u3;
    *(uint4*)(wsp + (size_t)(o * W_ + xbase + x2) * 8) = pk;
  }
}

// ---------------------------------------------------------------------------
// Kernel 2: 1x1 channel mix via MFMA, A (=w3) resident in registers, no LDS.
// Wave w owns output channels [32w, 32w+32); block covers 256 pixels.
// ---------------------------------------------------------------------------
__global__ __launch_bounds__(256) void k_mix(
    const float* __restrict__ x,
    const float* __restrict__ w3, const float* __restrict__ b3,
    const unsigned short* __restrict__ ws,
    float* __restrict__ out)
{
  const int t = threadIdx.x;
  const int wv = t >> 6, lane = t & 63, q = lane >> 4, lp = lane & 15;
  const int n = blockIdx.y;
  const int px0 = blockIdx.x * 256;

  // A fragments: rows o = 32*wv + 16*m + lp, k-slice ks*32 + q*8 (bf16-packed)
  s8v A[2][4];
  float b3v[2][4];
#pragma unroll
  for (int m = 0; m < 2; ++m) {
    const int o = 32 * wv + 16 * m + lp;
#pragma unroll
    for (int ks = 0; ks < 4; ++ks) {
      const float* src = w3 + o * 128 + ks * 32 + q * 8;
      float4 f0 = *(const float4*)src;
      float4 f1 = *(const float4*)(src + 4);
      union { s8v v; unsigned u[4]; } pk;
      pk.u[0] = f2bf(f0.x) | (f2bf(f0.y) << 16);
      pk.u[1] = f2bf(f0.z) | (f2bf(f0.w) << 16);
      pk.u[2] = f2bf(f1.x) | (f2bf(f1.y) << 16);
      pk.u[3] = f2bf(f1.z) | (f2bf(f1.w) << 16);
      A[m][ks] = pk.v;
    }
#pragma unroll
    for (int r = 0; r < 4; ++r) b3v[m][r] = b3[32 * wv + 16 * m + 4 * q + r];
  }

  const unsigned short* wsn = ws + (size_t)n * 16 * HW_ * 8;

#pragma unroll 2
  for (int npg = 0; npg < 16; ++npg) {
    const int pp = px0 + npg * 16 + lp;
    s8v B[4];
#pragma unroll
    for (int ks = 0; ks < 4; ++ks) {
      const int gg = ks * 4 + q;                 // channel-group for k = ks*32+q*8
      B[ks] = *(const s8v*)(wsn + ((size_t)gg * HW_ + pp) * 8);
    }
    f4v acc[2] = {{0.f,0.f,0.f,0.f},{0.f,0.f,0.f,0.f}};
#pragma unroll
    for (int ks = 0; ks < 4; ++ks) {
#pragma unroll
      for (int m = 0; m < 2; ++m)
        acc[m] = __builtin_amdgcn_mfma_f32_16x16x32_bf16(A[m][ks], B[ks], acc[m], 0, 0, 0);
    }
#pragma unroll
    for (int m = 0; m < 2; ++m)
#pragma unroll
      for (int r = 0; r < 4; ++r) {
        const int o = 32 * wv + 16 * m + 4 * q + r;   // D row = q*4+r
        const size_t idx = ((size_t)(n * C_ + o) << 14) + pp;
        out[idx] = (acc[m][r] + b3v[m][r]) * x[idx];
      }
  }
}

extern "C" void kernel_launch(void* const* d_in, const int* in_sizes, int n_in,
                              void* d_out, int out_size, void* d_ws, size_t ws_size,
                              hipStream_t stream) {
  const float* x   = (const float*)d_in[0];
  const float* w0  = (const float*)d_in[1];
  const float* b0  = (const float*)d_in[2];
  const float* w01 = (const float*)d_in[3];
  const float* b01 = (const float*)d_in[4];
  const float* w02 = (const float*)d_in[5];
  const float* b02 = (const float*)d_in[6];
  const float* w11 = (const float*)d_in[7];
  const float* b11 = (const float*)d_in[8];
  const float* w12 = (const float*)d_in[9];
  const float* b12 = (const float*)d_in[10];
  const float* w3  = (const float*)d_in[11];
  const float* b3  = (const float*)d_in[12];
  unsigned short* ws = (unsigned short*)d_ws;   // 16*16*16384*8*2 = 64 MiB
  float* out = (float*)d_out;

  dim3 g1(4, 16, 16);      // (x-strips, channel groups, batch)
  k_dw<<<g1, 256, 0, stream>>>(x, w0, b0, w01, b01, w02, b02, w11, b11, w12, b12, ws);

  dim3 g2(64, 16);         // (256-px blocks, batch)
  k_mix<<<g2, 256, 0, stream>>>(x, w3, b3, ws, out);
}